// Round 1
// 1238.178 us; speedup vs baseline: 1.1968x; 1.1968x over previous
//
#include <hip/hip_runtime.h>
#include <hip/hip_bf16.h>
#include <cstdint>

#define VOCAB 50257
#define HID   256
#define BT    4096

typedef __bf16 bf16x8 __attribute__((ext_vector_type(8)));
typedef float  f32x4  __attribute__((ext_vector_type(4)));

// global -> LDS async copy, 16 B per lane. LDS dest is wave-uniform base +
// lane*16 (HW rule, m104/m108); global src is per-lane.
__device__ __forceinline__ void async_copy16(void* lds, const void* gmem) {
  auto g = (const __attribute__((address_space(1))) void*)(uintptr_t)gmem;
  auto l = (__attribute__((address_space(3))) void*)(uint32_t)(uintptr_t)lds;
  __builtin_amdgcn_global_load_lds(g, l, 16, 0, 0);
}

// ---------------- kernel 1: W2 fp32 -> bf16 ----------------
__global__ void k_w2_bf16(const float* __restrict__ w2,
                          __hip_bfloat16* __restrict__ w2b, int n4) {
  int i = blockIdx.x * blockDim.x + threadIdx.x;
  if (i >= n4) return;
  float4 v = ((const float4*)w2)[i];
  union { __hip_bfloat16 h[4]; uint2 u; } o;
  o.h[0] = __float2bfloat16(v.x); o.h[1] = __float2bfloat16(v.y);
  o.h[2] = __float2bfloat16(v.z); o.h[3] = __float2bfloat16(v.w);
  ((uint2*)w2b)[i] = o.u;
}

// ---------------- kernel 2: x = relu(W1.T[idx] + b1) -> bf16 ----------------
__global__ void k_build_x(const int* __restrict__ idx, const float* __restrict__ w1,
                          const float* __restrict__ b1, __hip_bfloat16* __restrict__ xb) {
  int t = blockIdx.x, h = threadIdx.x;
  int id = idx[t];
  float v = w1[(size_t)h * VOCAB + id] + b1[h];
  v = fmaxf(v, 0.f);
  xb[t * HID + h] = __float2bfloat16(v);
}

__global__ void k_zero(float* p, int n) {
  int i = blockIdx.x * 256 + threadIdx.x;
  if (i < n) p[i] = 0.f;
}

// ---------------- kernel 3: GEMM (x @ W2^T + b2) + fused CE partials ---------
// 128x128 tile, BK=64, 4 waves, 16x16x32 bf16 MFMA, 4x4 frags per wave.
// GEMM LDS layout XOR-swizzled (source-permuted, dest linear per m104/m108).
// Epilogue: two-pass LDS transpose (64x132 f32 tile aliased over As/Bs) so
// logits stores are 64-lane-contiguous (256 B/instr, full 128 B lines via L2).
// Rationale: previous 4 B/lane nt stores produced half-line HBM bursts ->
// WRITE_SIZE was 2x the 824 MB of unique logits and the kernel stalled on
// store drain (MfmaUtil 5.6%, VALU 10%, HBM 29% all idle).
__global__ __launch_bounds__(256) void k_gemm_ce(
    const __hip_bfloat16* __restrict__ xb,   // [BT][HID]
    const __hip_bfloat16* __restrict__ w2b,  // [VOCAB][HID]
    const float* __restrict__ b2,            // [VOCAB]
    const int* __restrict__ targets,         // [BT]
    float* __restrict__ logits,              // [BT][VOCAB]
    float* __restrict__ sumexp,              // [BT], pre-zeroed
    float* __restrict__ tlog)                // [BT]
{
  __shared__ __align__(16) union SMem {
    struct { unsigned short As[128 * 64]; unsigned short Bs[128 * 64]; } ab;
    float tile[64 * 132];   // 33792 B; pad 132 keeps LDS banks 2-way (free)
  } sm;
  __shared__ float rowsum[128];
  __shared__ int   tgts[128];

  const int tid  = threadIdx.x;
  const int lane = tid & 63, wave = tid >> 6;
  const int quad = lane >> 4, l15 = lane & 15;
  const int wrow = wave >> 1, wcol = wave & 1;

  const int bx   = blockIdx.x;
  const int mt   = bx & 31;      // 32 M-tiles (4096/128); n-major order so
  const int nt   = bx >> 5;      // consecutive blocks share the same W2 tile
  const int row0 = mt * 128;
  const int col0 = nt * 128;

  // --- staging constants (per lane) ---
  const int srow = lane >> 3;              // row within an 8-row chunk
  const int scb  = (lane & 7) ^ srow;      // swizzled source col-block

  const __hip_bfloat16* aSrc[4];
  const __hip_bfloat16* bSrc[4];
  unsigned short* aDst[4];
  unsigned short* bDst[4];
#pragma unroll
  for (int i = 0; i < 4; ++i) {
    int ar = row0 + wave * 32 + i * 8 + srow;                 // < 4096 always
    aSrc[i] = xb + (size_t)ar * HID + scb * 8;
    int br = col0 + wave * 32 + i * 8 + srow;
    if (br > VOCAB - 1) br = VOCAB - 1;                       // tail clamp
    bSrc[i] = w2b + (size_t)br * HID + scb * 8;
    aDst[i] = sm.ab.As + (wave * 4 + i) * 512;                // chunk base
    bDst[i] = sm.ab.Bs + (wave * 4 + i) * 512;
  }

  f32x4 acc[4][4];
#pragma unroll
  for (int a = 0; a < 4; ++a)
#pragma unroll
    for (int b = 0; b < 4; ++b) acc[a][b] = (f32x4){0.f, 0.f, 0.f, 0.f};

  int arow[4], brow[4];
#pragma unroll
  for (int i = 0; i < 4; ++i) {
    arow[i] = wrow * 64 + i * 16 + l15;
    brow[i] = wcol * 64 + i * 16 + l15;
  }

#pragma unroll
  for (int kk = 0; kk < 4; ++kk) {
    const int k0 = kk * 64;
#pragma unroll
    for (int i = 0; i < 4; ++i) {
      async_copy16(aDst[i], aSrc[i] + k0);
      async_copy16(bDst[i], bSrc[i] + k0);
    }
    __syncthreads();   // compiler emits s_waitcnt vmcnt(0) before s_barrier
#pragma unroll
    for (int ks = 0; ks < 2; ++ks) {
      bf16x8 af[4], bfr[4];
      const int cb = ks * 4 + quad;
#pragma unroll
      for (int i = 0; i < 4; ++i) {
        af[i]  = *(const bf16x8*)(sm.ab.As + arow[i] * 64 + ((cb ^ (arow[i] & 7)) * 8));
        bfr[i] = *(const bf16x8*)(sm.ab.Bs + brow[i] * 64 + ((cb ^ (brow[i] & 7)) * 8));
      }
#pragma unroll
      for (int mi = 0; mi < 4; ++mi)
#pragma unroll
        for (int ni = 0; ni < 4; ++ni)
          acc[mi][ni] = __builtin_amdgcn_mfma_f32_16x16x32_bf16(
              af[mi], bfr[ni], acc[mi][ni], 0, 0, 0);
    }
    __syncthreads();
  }
  // (loop ends with a barrier: As/Bs are dead, safe to alias as the f32 tile)

  // ---------------- epilogue: LDS transpose -> contiguous stores -------------
  float b2v[4];
#pragma unroll
  for (int ni = 0; ni < 4; ++ni) {
    int c = col0 + wcol * 64 + ni * 16 + l15;
    b2v[ni] = b2[c < VOCAB ? c : VOCAB - 1];
  }
  if (tid < 128) { tgts[tid] = targets[row0 + tid]; rowsum[tid] = 0.f; }

  const int col   = tid & 127;          // column within the 128-wide tile
  const int cg    = col0 + col;         // global column
  const bool okc  = cg < VOCAB;
  const int rhalf = tid >> 7;           // 0: even local row, 1: odd local row

#pragma unroll
  for (int pass = 0; pass < 2; ++pass) {
    if (pass) __syncthreads();          // pass-0 tile reads done before overwrite
    if (wrow == pass) {
      // producer waves deposit their 64x128 half (+bias) into the f32 tile.
      // banks: (132*(4q+r) + 16ni + l15) % 32 -> 2 lanes/bank = free.
#pragma unroll
      for (int mi = 0; mi < 4; ++mi)
#pragma unroll
        for (int ni = 0; ni < 4; ++ni) {
          const int lcol = wcol * 64 + ni * 16 + l15;
#pragma unroll
          for (int r = 0; r < 4; ++r) {
            const int lrow = mi * 16 + quad * 4 + r;
            sm.tile[lrow * 132 + lcol] = acc[mi][ni][r] + b2v[ni];
          }
        }
    }
    __syncthreads();                    // tile (+tgts/rowsum on pass 0) visible

    // stream 64 rows x 128 cols: each wave = ONE row per step, 64 lanes over
    // consecutive columns -> each store instruction is 256 B contiguous.
#pragma unroll 4
    for (int k = 0; k < 32; ++k) {
      const int lrow = 2 * k + rhalf;           // 0..63
      const int rowl = pass * 64 + lrow;        // 0..127
      const int rowg = row0 + rowl;
      const float v  = sm.tile[lrow * 132 + col];
      float p = 0.f;
      if (okc) {
        logits[(size_t)rowg * VOCAB + cg] = v;  // plain store: L2 merges lines
        p = __expf(v);
        if (cg == tgts[rowl]) tlog[rowg] = v;   // unique writer globally
      }
      // whole wave shares this row: full 64-lane reduction
      p += __shfl_xor(p, 1);
      p += __shfl_xor(p, 2);
      p += __shfl_xor(p, 4);
      p += __shfl_xor(p, 8);
      p += __shfl_xor(p, 16);
      p += __shfl_xor(p, 32);
      if (lane == 0) atomicAdd(&rowsum[rowl], p);
    }
  }
  __syncthreads();
  if (tid < 128) atomicAdd(&sumexp[row0 + tid], rowsum[tid]);
}

// ---------------- kernel 4: loss = mean(log(sumexp) - tlogit) ----------------
__global__ void k_loss(const float* __restrict__ sumexp,
                       const float* __restrict__ tlog, float* __restrict__ out) {
  __shared__ float red[4];
  float s = 0.f;
  for (int t = threadIdx.x; t < BT; t += 256)
    s += logf(sumexp[t]) - tlog[t];
#pragma unroll
  for (int m = 1; m < 64; m <<= 1) s += __shfl_xor(s, m);
  if ((threadIdx.x & 63) == 0) red[threadIdx.x >> 6] = s;
  __syncthreads();
  if (threadIdx.x == 0)
    out[0] = (red[0] + red[1] + red[2] + red[3]) * (1.0f / BT);
}

extern "C" void kernel_launch(void* const* d_in, const int* in_sizes, int n_in,
                              void* d_out, int out_size, void* d_ws, size_t ws_size,
                              hipStream_t stream) {
  const int*   idx = (const int*)d_in[0];
  const int*   tgt = (const int*)d_in[1];
  const float* W1  = (const float*)d_in[2];
  const float* b1  = (const float*)d_in[3];
  const float* W2  = (const float*)d_in[4];
  const float* b2  = (const float*)d_in[5];
  float* out = (float*)d_out;

  char* ws = (char*)d_ws;
  __hip_bfloat16* w2b = (__hip_bfloat16*)ws;                              // 25.7 MB
  __hip_bfloat16* xb  = (__hip_bfloat16*)(ws + (size_t)VOCAB * HID * 2);  // 2 MB
  float* sumexp = (float*)(ws + (size_t)VOCAB * HID * 2 + (size_t)BT * HID * 2);
  float* tlog   = sumexp + BT;

  const int n4 = VOCAB * HID / 4;
  k_w2_bf16<<<(n4 + 255) / 256, 256, 0, stream>>>(W2, w2b, n4);
  k_build_x<<<BT, HID, 0, stream>>>(idx, W1, b1, xb);
  k_zero<<<(BT + 255) / 256, 256, 0, stream>>>(sumexp, BT);
  k_gemm_ce<<<393 * 32, 256, 0, stream>>>(xb, w2b, b2, tgt, out, sumexp, tlog);
  k_loss<<<1, 256, 0, stream>>>(sumexp, tlog, out + (size_t)BT * VOCAB);
}

// Round 2
// 1095.352 us; speedup vs baseline: 1.3529x; 1.1304x over previous
//
#include <hip/hip_runtime.h>
#include <hip/hip_bf16.h>
#include <cstdint>

#define VOCAB 50257
#define HID   256
#define BT    4096

typedef __bf16 bf16x8 __attribute__((ext_vector_type(8)));
typedef float  f32x4  __attribute__((ext_vector_type(4)));

// global -> LDS async copy, 16 B per lane. LDS dest is wave-uniform base +
// lane*16 (HW rule, m104/m108); global src is per-lane.
__device__ __forceinline__ void async_copy16(void* lds, const void* gmem) {
  auto g = (const __attribute__((address_space(1))) void*)(uintptr_t)gmem;
  auto l = (__attribute__((address_space(3))) void*)(uint32_t)(uintptr_t)lds;
  __builtin_amdgcn_global_load_lds(g, l, 16, 0, 0);
}

// ---------------- kernel 1: W2 fp32 -> bf16 ----------------
__global__ void k_w2_bf16(const float* __restrict__ w2,
                          __hip_bfloat16* __restrict__ w2b, int n4) {
  int i = blockIdx.x * blockDim.x + threadIdx.x;
  if (i >= n4) return;
  float4 v = ((const float4*)w2)[i];
  union { __hip_bfloat16 h[4]; uint2 u; } o;
  o.h[0] = __float2bfloat16(v.x); o.h[1] = __float2bfloat16(v.y);
  o.h[2] = __float2bfloat16(v.z); o.h[3] = __float2bfloat16(v.w);
  ((uint2*)w2b)[i] = o.u;
}

// ---------------- kernel 2: x = relu(W1.T[idx] + b1) -> bf16 ----------------
__global__ void k_build_x(const int* __restrict__ idx, const float* __restrict__ w1,
                          const float* __restrict__ b1, __hip_bfloat16* __restrict__ xb) {
  int t = blockIdx.x, h = threadIdx.x;
  int id = idx[t];
  float v = w1[(size_t)h * VOCAB + id] + b1[h];
  v = fmaxf(v, 0.f);
  xb[t * HID + h] = __float2bfloat16(v);
}

__global__ void k_zero(float* p, int n) {
  int i = blockIdx.x * 256 + threadIdx.x;
  if (i < n) p[i] = 0.f;
}

// ---------------- kernel 3: GEMM (x @ W2^T + b2) + fused CE partials ---------
// 128x128 tile, BK=64, 4 waves, 16x16x32 bf16 MFMA, 4x4 frags per wave.
// GEMM LDS layout XOR-swizzled (source-permuted, dest linear per m104/m108).
//
// Epilogue v3: the v2 streaming loop carried exp + 6x shfl + LDS atomic per
// 4 B stored (384 DS-shfl/thread) and dominated the per-CU LDS pipe.  Now:
//   - exp/rowsum/tlog computed in acc-register space (4 shfl per row group,
//     64 shfl/thread total, 16 LDS atomics),
//   - transpose tile is col-major [128col][64row], rows XOR-swizzled
//     (phys = r4 ^ ((col&15)<<2), b128-alignment-preserving), so producers
//     ds_write_b128 x16 and streamers ds_read_b128 x16 (was 64+64 b32),
//   - streaming loop is a pure copy: 1 b128 LDS read -> 4 row-contiguous
//     256 B store instructions (full 128 B lines via L2 merge; plain stores,
//     not nt -- row bases are 68 mod 128 B).
__global__ __launch_bounds__(256) void k_gemm_ce(
    const __hip_bfloat16* __restrict__ xb,   // [BT][HID]
    const __hip_bfloat16* __restrict__ w2b,  // [VOCAB][HID]
    const float* __restrict__ b2,            // [VOCAB]
    const int* __restrict__ targets,         // [BT]
    float* __restrict__ logits,              // [BT][VOCAB]
    float* __restrict__ sumexp,              // [BT], pre-zeroed
    float* __restrict__ tlog)                // [BT]
{
  __shared__ __align__(16) union SMem {
    struct { unsigned short As[128 * 64]; unsigned short Bs[128 * 64]; } ab;
    float tile[128 * 64];   // col-major [col][row], XOR-swizzled rows; 32 KB
  } sm;
  __shared__ float rowsum[128];
  __shared__ int   tgts[128];

  const int tid  = threadIdx.x;
  const int lane = tid & 63, wave = tid >> 6;
  const int quad = lane >> 4, l15 = lane & 15;
  const int wrow = wave >> 1, wcol = wave & 1;

  const int bx   = blockIdx.x;
  const int mt   = bx & 31;      // 32 M-tiles (4096/128); n-major order so
  const int nt   = bx >> 5;      // consecutive blocks share the same W2 tile
  const int row0 = mt * 128;
  const int col0 = nt * 128;

  // --- staging constants (per lane) ---
  const int srow = lane >> 3;              // row within an 8-row chunk
  const int scb  = (lane & 7) ^ srow;      // swizzled source col-block

  const __hip_bfloat16* aSrc[4];
  const __hip_bfloat16* bSrc[4];
  unsigned short* aDst[4];
  unsigned short* bDst[4];
#pragma unroll
  for (int i = 0; i < 4; ++i) {
    int ar = row0 + wave * 32 + i * 8 + srow;                 // < 4096 always
    aSrc[i] = xb + (size_t)ar * HID + scb * 8;
    int br = col0 + wave * 32 + i * 8 + srow;
    if (br > VOCAB - 1) br = VOCAB - 1;                       // tail clamp
    bSrc[i] = w2b + (size_t)br * HID + scb * 8;
    aDst[i] = sm.ab.As + (wave * 4 + i) * 512;                // chunk base
    bDst[i] = sm.ab.Bs + (wave * 4 + i) * 512;
  }

  f32x4 acc[4][4];
#pragma unroll
  for (int a = 0; a < 4; ++a)
#pragma unroll
    for (int b = 0; b < 4; ++b) acc[a][b] = (f32x4){0.f, 0.f, 0.f, 0.f};

  int arow[4], brow[4];
#pragma unroll
  for (int i = 0; i < 4; ++i) {
    arow[i] = wrow * 64 + i * 16 + l15;
    brow[i] = wcol * 64 + i * 16 + l15;
  }

#pragma unroll
  for (int kk = 0; kk < 4; ++kk) {
    const int k0 = kk * 64;
#pragma unroll
    for (int i = 0; i < 4; ++i) {
      async_copy16(aDst[i], aSrc[i] + k0);
      async_copy16(bDst[i], bSrc[i] + k0);
    }
    __syncthreads();   // compiler emits s_waitcnt vmcnt(0) before s_barrier
#pragma unroll
    for (int ks = 0; ks < 2; ++ks) {
      bf16x8 af[4], bfr[4];
      const int cb = ks * 4 + quad;
#pragma unroll
      for (int i = 0; i < 4; ++i) {
        af[i]  = *(const bf16x8*)(sm.ab.As + arow[i] * 64 + ((cb ^ (arow[i] & 7)) * 8));
        bfr[i] = *(const bf16x8*)(sm.ab.Bs + brow[i] * 64 + ((cb ^ (brow[i] & 7)) * 8));
      }
#pragma unroll
      for (int mi = 0; mi < 4; ++mi)
#pragma unroll
        for (int ni = 0; ni < 4; ++ni)
          acc[mi][ni] = __builtin_amdgcn_mfma_f32_16x16x32_bf16(
              af[mi], bfr[ni], acc[mi][ni], 0, 0, 0);
    }
    __syncthreads();   // final barrier: As/Bs dead after this -> tile may alias
  }

  // ---------------- epilogue ------------------------------------------------
  float b2v[4];
  int   colg[4];
  bool  okc[4];
#pragma unroll
  for (int ni = 0; ni < 4; ++ni) {
    int c = col0 + wcol * 64 + ni * 16 + l15;
    colg[ni] = c;
    okc[ni]  = c < VOCAB;
    b2v[ni]  = b2[okc[ni] ? c : VOCAB - 1];
  }
  if (tid < 128) { tgts[tid] = targets[row0 + tid]; rowsum[tid] = 0.f; }
  __syncthreads();   // tgts/rowsum visible

  // --- exp-sum + target gather in acc space (rows live in 16-lane groups) ---
#pragma unroll
  for (int mi = 0; mi < 4; ++mi) {
#pragma unroll
    for (int r = 0; r < 4; ++r) {
      const int rowl = wrow * 64 + mi * 16 + quad * 4 + r;
      const int rowg = row0 + rowl;
      const int tg   = tgts[rowl];
      float p = 0.f;
#pragma unroll
      for (int ni = 0; ni < 4; ++ni) {
        if (okc[ni]) {
          float v = acc[mi][ni][r] + b2v[ni];
          acc[mi][ni][r] = v;               // biased value feeds the store pass
          p += __expf(v);
          if (colg[ni] == tg) tlog[rowg] = v;   // unique writer globally
        }
      }
      p += __shfl_xor(p, 1);
      p += __shfl_xor(p, 2);
      p += __shfl_xor(p, 4);
      p += __shfl_xor(p, 8);
      if (l15 == 0) atomicAdd(&rowsum[rowl], p);
    }
  }

  // --- two-pass transpose -> contiguous logits stores -----------------------
  const int scol  = (wave & 1) * 64 + lane;   // streamed tile column, 0..127
  const int cgs   = col0 + scol;
  const bool oks  = cgs < VOCAB;
  const int rbase = (wave >> 1) * 32;         // streamed row base within half
  const int sxor  = (scol & 15) << 2;

  // pass 0 produce (rows 0..63) overlaps the tail of other waves' reduction
  if (wrow == 0) {
#pragma unroll
    for (int mi = 0; mi < 4; ++mi)
#pragma unroll
      for (int ni = 0; ni < 4; ++ni) {
        const int c  = wcol * 64 + ni * 16 + l15;
        const int pr = (mi * 16 + quad * 4) ^ ((c & 15) << 2);
        *(f32x4*)&sm.tile[c * 64 + pr] = acc[mi][ni];
      }
  }
  __syncthreads();   // tile ready + all rowsum atomics done

  if (tid < 128) atomicAdd(&sumexp[row0 + tid], rowsum[tid]);

#pragma unroll
  for (int k = 0; k < 8; ++k) {
    const int r4 = rbase + k * 4;
    f32x4 v = *(const f32x4*)&sm.tile[scol * 64 + (r4 ^ sxor)];
    if (oks) {
      const size_t base = (size_t)(row0 + r4) * VOCAB + cgs;
#pragma unroll
      for (int j = 0; j < 4; ++j)
        logits[base + (size_t)j * VOCAB] = v[j];
    }
  }
  __syncthreads();   // pass-0 reads done before overwrite

  if (wrow == 1) {
#pragma unroll
    for (int mi = 0; mi < 4; ++mi)
#pragma unroll
      for (int ni = 0; ni < 4; ++ni) {
        const int c  = wcol * 64 + ni * 16 + l15;
        const int pr = (mi * 16 + quad * 4) ^ ((c & 15) << 2);
        *(f32x4*)&sm.tile[c * 64 + pr] = acc[mi][ni];
      }
  }
  __syncthreads();

#pragma unroll
  for (int k = 0; k < 8; ++k) {
    const int r4 = rbase + k * 4;
    f32x4 v = *(const f32x4*)&sm.tile[scol * 64 + (r4 ^ sxor)];
    if (oks) {
      const size_t base = (size_t)(row0 + 64 + r4) * VOCAB + cgs;
#pragma unroll
      for (int j = 0; j < 4; ++j)
        logits[base + (size_t)j * VOCAB] = v[j];
    }
  }
}

// ---------------- kernel 4: loss = mean(log(sumexp) - tlogit) ----------------
__global__ void k_loss(const float* __restrict__ sumexp,
                       const float* __restrict__ tlog, float* __restrict__ out) {
  __shared__ float red[4];
  float s = 0.f;
  for (int t = threadIdx.x; t < BT; t += 256)
    s += logf(sumexp[t]) - tlog[t];
#pragma unroll
  for (int m = 1; m < 64; m <<= 1) s += __shfl_xor(s, m);
  if ((threadIdx.x & 63) == 0) red[threadIdx.x >> 6] = s;
  __syncthreads();
  if (threadIdx.x == 0)
    out[0] = (red[0] + red[1] + red[2] + red[3]) * (1.0f / BT);
}

extern "C" void kernel_launch(void* const* d_in, const int* in_sizes, int n_in,
                              void* d_out, int out_size, void* d_ws, size_t ws_size,
                              hipStream_t stream) {
  const int*   idx = (const int*)d_in[0];
  const int*   tgt = (const int*)d_in[1];
  const float* W1  = (const float*)d_in[2];
  const float* b1  = (const float*)d_in[3];
  const float* W2  = (const float*)d_in[4];
  const float* b2  = (const float*)d_in[5];
  float* out = (float*)d_out;

  char* ws = (char*)d_ws;
  __hip_bfloat16* w2b = (__hip_bfloat16*)ws;                              // 25.7 MB
  __hip_bfloat16* xb  = (__hip_bfloat16*)(ws + (size_t)VOCAB * HID * 2);  // 2 MB
  float* sumexp = (float*)(ws + (size_t)VOCAB * HID * 2 + (size_t)BT * HID * 2);
  float* tlog   = sumexp + BT;

  const int n4 = VOCAB * HID / 4;
  k_w2_bf16<<<(n4 + 255) / 256, 256, 0, stream>>>(W2, w2b, n4);
  k_build_x<<<BT, HID, 0, stream>>>(idx, W1, b1, xb);
  k_zero<<<(BT + 255) / 256, 256, 0, stream>>>(sumexp, BT);
  k_gemm_ce<<<393 * 32, 256, 0, stream>>>(xb, w2b, b2, tgt, out, sumexp, tlog);
  k_loss<<<1, 256, 0, stream>>>(sumexp, tlog, out + (size_t)BT * VOCAB);
}